// Round 12
// baseline (153.123 us; speedup 1.0000x reference)
//
#include <hip/hip_runtime.h>
#include <hip/hip_bf16.h>

// Problem constants (match reference: shape=[15,400,400], batch_size=2)
#define DD 15
#define HH 400
#define WW 400
#define CIN 32
#define COUT 64
#define KK 27
#define NVOX (2 * DD * HH * WW)        // 4,800,000
#define NWORDS (NVOX / 64)              // 75,000 bitmap words
#define CAP 32768                       // per-k pair capacity (actual ~8.3k), mult of 128
#define CNT_STRIDE 64                   // one counter per 256B line
#define OFFC_GRID 2048
#define PCAP 262144                     // total pair slots (actual ~217k)
#define SCAN_B 1024                     // elements per scan3 block

typedef short bf16x8 __attribute__((ext_vector_type(8)));
typedef float f32x4  __attribute__((ext_vector_type(4)));

__device__ inline short f2bf(float f) {               // f32 -> bf16 RNE
    unsigned u = __float_as_uint(f);
    return (short)((u + 0x7FFFu + ((u >> 16) & 1u)) >> 16);
}
__device__ inline float bflo(unsigned u) { return __uint_as_float(u << 16); }
__device__ inline float bfhi(unsigned u) { return __uint_as_float(u & 0xFFFF0000u); }

// ---------- init: bitmap = 0, cnt = 0, done = 0 ---------------------------------------
__global__ void init_kernel(unsigned long long* __restrict__ bitmap,
                            int* __restrict__ cnt, int* __restrict__ done) {
    int t = blockIdx.x * blockDim.x + threadIdx.x;
    if (t < KK * CNT_STRIDE) cnt[t] = 0;
    if (blockIdx.x == 0 && threadIdx.x == 0) *done = 0;
    int stride = gridDim.x * blockDim.x;
    for (int w = t; w < NWORDS; w += stride) bitmap[w] = 0ull;
}

// ---------- fill: flats[i] = flat(coors[i]); set presence bit -------------------------
__global__ void fill_kernel(const int* __restrict__ coors,
                            int* __restrict__ flats,
                            unsigned long long* __restrict__ bitmap, int n) {
    int i = blockIdx.x * blockDim.x + threadIdx.x;
    if (i >= n) return;
    int b = coors[i * 4 + 0];
    int z = coors[i * 4 + 1];
    int y = coors[i * 4 + 2];
    int x = coors[i * 4 + 3];
    int f = ((b * DD + z) * HH + y) * WW + x;
    flats[i] = f;
    atomicOr(&bitmap[f >> 6], 1ull << (f & 63));
}

// ---------- prefix[w] = lower_bound(flats, w*64)  (rank base per bitmap word) ---------
__global__ void prefix_kernel(const int* __restrict__ flats,
                              int* __restrict__ prefix, int n) {
    int w = blockIdx.x * blockDim.x + threadIdx.x;
    if (w >= NWORDS) return;
    int target = w << 6;
    int lo = 0, hi = n;
    while (lo < hi) {
        int mid = (lo + hi) >> 1;
        if (flats[mid] < target) lo = mid + 1; else hi = mid;
    }
    prefix[w] = lo;
}

__device__ inline bool bm_test(const unsigned long long* __restrict__ bitmap, int f) {
    return (bitmap[f >> 6] >> (f & 63)) & 1ull;
}
__device__ inline int bm_rank(const unsigned long long* __restrict__ bitmap,
                              const int* __restrict__ prefix, int f) {
    int w = f >> 6, b = f & 63;       // bit known set
    unsigned long long m = bitmap[w];
    return prefix[w] + __popcll(m & ((1ull << b) - 1ull));
}

// ---------- pair lists + per-block percnt sums + last-block sentinel padding ----------
__global__ __launch_bounds__(256) void build_pairs_kernel(
        const int* __restrict__ flats,
        const unsigned long long* __restrict__ bitmap,
        const int* __restrict__ prefix,
        int* __restrict__ cnt, int2* __restrict__ pairIJ,
        int* __restrict__ percnt, int* __restrict__ bsum256,
        int* __restrict__ done, int n) {
    __shared__ int lcnt[KK];
    __shared__ int lbase[KK];
    __shared__ int lpos[KK];
    __shared__ int red[256];
    __shared__ int lticket;
    __shared__ int cks[KK];
    int i = blockIdx.x * blockDim.x + threadIdx.x;
    if (threadIdx.x < KK) { lcnt[threadIdx.x] = 0; lpos[threadIdx.x] = 0; }
    __syncthreads();

    int f0 = 0, x = 0;
    unsigned vmask = 0;                // 27-bit tap-validity mask
    bool act = (i < n);
    if (act) {
        f0 = flats[i];
        x = f0 % WW;
        int rem = f0 / WW;             // (b*DD+z)*HH + y
        int y = rem % HH;
        int z = (rem / HH) % DD;
#pragma unroll
        for (int p = 0; p < 9; ++p) {
            int dz = p / 3 - 1, dy = p % 3 - 1;
            int zn = z + dz, yn = y + dy;
            if (zn < 0 || zn >= DD || yn < 0 || yn >= HH) continue;
            int fn = f0 + dz * (HH * WW) + dy * WW;
            int kb = p * 3;
            if (x > 0 && bm_test(bitmap, fn - 1)) {
                vmask |= 1u << kb; atomicAdd(&lcnt[kb], 1);
            }
            if (kb + 1 != 13 && bm_test(bitmap, fn)) {
                vmask |= 1u << (kb + 1); atomicAdd(&lcnt[kb + 1], 1);
            }
            if (x < WW - 1 && bm_test(bitmap, fn + 1)) {
                vmask |= 1u << (kb + 2); atomicAdd(&lcnt[kb + 2], 1);
            }
        }
        percnt[i] = __popc(vmask);
    }
    red[threadIdx.x] = act ? (int)__popc(vmask) : 0;
    __syncthreads();
    // global reservations (one atomic per block per k)
    if (threadIdx.x < KK && lcnt[threadIdx.x] > 0)
        lbase[threadIdx.x] = atomicAdd(&cnt[threadIdx.x * CNT_STRIDE], lcnt[threadIdx.x]);
    // block-sum of percnt -> bsum256 (replaces scan1 kernel)
    for (int o = 128; o > 0; o >>= 1) {
        if ((int)threadIdx.x < o) red[threadIdx.x] += red[threadIdx.x + o];
        __syncthreads();
    }
    if (threadIdx.x == 0) bsum256[blockIdx.x] = red[0];
    __syncthreads();
    // emit (positions unique within block; recompute rank from L1-hot words)
    if (act && vmask) {
        int lt = 0;                    // thread-local slot within voxel i's CSR segment
#pragma unroll
        for (int p = 0; p < 9; ++p) {
            int kb = p * 3;
            if (!(vmask & (7u << kb))) continue;
            int dz = p / 3 - 1, dy = p % 3 - 1;
            int fn = f0 + dz * (HH * WW) + dy * WW;
#pragma unroll
            for (int d = 0; d < 3; ++d) {
                int k = kb + d;
                if (!(vmask & (1u << k))) continue;
                int j = bm_rank(bitmap, prefix, fn + d - 1);
                int pos = lbase[k] + atomicAdd(&lpos[k], 1);
                if (pos < CAP) pairIJ[k * CAP + pos] = make_int2((i << 5) | lt, j);
                ++lt;
            }
        }
    }
    // last-block sentinel padding (replaces pad kernel)
    __syncthreads();
    if (threadIdx.x == 0) lticket = atomicAdd(done, 1);
    __syncthreads();
    if (lticket == (int)gridDim.x - 1) {
        if (threadIdx.x < KK)          // coherent read of final counts (cross-XCD safe)
            cks[threadIdx.x] = atomicAdd(&cnt[threadIdx.x * CNT_STRIDE], 0);
        __syncthreads();
        for (int k = 0; k < KK; ++k) {
            int ck = min(cks[k], CAP);
            int ckp = min((ck + 127) & ~127, CAP);
            for (int pos = ck + (int)threadIdx.x; pos < ckp; pos += 256)
                pairIJ[k * CAP + pos] = make_int2(n << 5, 0);   // sentinel
        }
    }
}

// ---------- scan3: rowptr = exclusive prefix of percnt (base from bsum256) ------------
__global__ void scan3_kernel(const int* __restrict__ pc, const int* __restrict__ bsum256,
                             int* __restrict__ rowptr, int n) {
    __shared__ int ts[256];
    __shared__ int bs[256];
    int lim = 4 * blockIdx.x;                  // build-blocks fully before this block
    int v = 0;
    for (int j = threadIdx.x; j < lim; j += 256) v += bsum256[j];
    bs[threadIdx.x] = v; __syncthreads();
    for (int o = 128; o > 0; o >>= 1) {
        if ((int)threadIdx.x < o) bs[threadIdx.x] += bs[threadIdx.x + o];
        __syncthreads();
    }
    int bbase = bs[0];

    int base = blockIdx.x * SCAN_B + threadIdx.x * 4;
    int e[4]; int s = 0;
#pragma unroll
    for (int u = 0; u < 4; ++u) {
        int idx = base + u;
        e[u] = (idx < n) ? pc[idx] : 0;
        s += e[u];
    }
    ts[threadIdx.x] = s; __syncthreads();
    for (int o = 1; o < 256; o <<= 1) {        // inclusive H-S scan
        int t = ((int)threadIdx.x >= o) ? ts[threadIdx.x - o] : 0;
        __syncthreads();
        ts[threadIdx.x] += t;
        __syncthreads();
    }
    int run = ts[threadIdx.x] - s + bbase;     // exclusive thread base
#pragma unroll
    for (int u = 0; u < 4; ++u) {
        int idx = base + u;
        if (idx < n) rowptr[idx] = run;
        run += e[u];
        if (idx == n - 1) rowptr[n] = run;
    }
}

// ---------- center tap (MFMA) + CSR partial reduce, 2 m-tiles per wave ----------------
template <int C, typename TIN, typename TOUT>
__global__ __launch_bounds__(256) void center_mfma_kernel(
        const TIN* __restrict__ xin, const float* __restrict__ Wc,  // Wc = W + 13*C*64
        const int* __restrict__ rowptr, const unsigned short* __restrict__ part,
        TOUT* __restrict__ xout, int n) {
    constexpr int KT = C / 32;
    int lane = threadIdx.x & 63;
    int mrow = lane & 15;            // A row / B col / D col
    int kgrp = lane >> 4;            // k-group (8 k's per group)
    int wid = (blockIdx.x * blockDim.x + threadIdx.x) >> 6;
    int nwaves = (gridDim.x * blockDim.x) >> 6;

    bf16x8 bf[KT][4];                // B fragments: [k-tile][n-tile]
#pragma unroll
    for (int kt = 0; kt < KT; ++kt)
#pragma unroll
        for (int nt = 0; nt < 4; ++nt)
#pragma unroll
            for (int j = 0; j < 8; ++j)
                bf[kt][nt][j] = f2bf(Wc[(kt * 32 + kgrp * 8 + j) * 64 + nt * 16 + mrow]);

    int ntiles = (n + 15) >> 4;
    int ntiles2 = (ntiles + 1) >> 1;

    auto body = [&](int t) {
        if (t >= ntiles) return;
        int row = t * 16 + mrow;
        f32x4 zero = {0.f, 0.f, 0.f, 0.f};
        bf16x8 a[KT];
        if (row < n) {
            if constexpr (sizeof(TIN) == 4) {
                const float* xr = (const float*)xin + (size_t)row * C + kgrp * 8;
#pragma unroll
                for (int kt = 0; kt < KT; ++kt) {
                    float4 x0 = *(const float4*)(xr + kt * 32);
                    float4 x1 = *(const float4*)(xr + kt * 32 + 4);
                    a[kt][0] = f2bf(x0.x); a[kt][1] = f2bf(x0.y);
                    a[kt][2] = f2bf(x0.z); a[kt][3] = f2bf(x0.w);
                    a[kt][4] = f2bf(x1.x); a[kt][5] = f2bf(x1.y);
                    a[kt][6] = f2bf(x1.z); a[kt][7] = f2bf(x1.w);
                }
            } else {
                const unsigned short* xr = (const unsigned short*)xin + (size_t)row * C + kgrp * 8;
#pragma unroll
                for (int kt = 0; kt < KT; ++kt)
                    a[kt] = *(const bf16x8*)(xr + kt * 32);
            }
        } else {
#pragma unroll
            for (int kt = 0; kt < KT; ++kt)
#pragma unroll
                for (int j = 0; j < 8; ++j) a[kt][j] = 0;
        }
        f32x4 acc[4];
#pragma unroll
        for (int nt = 0; nt < 4; ++nt) {
            acc[nt] = zero;
#pragma unroll
            for (int kt = 0; kt < KT; ++kt)
                acc[nt] = __builtin_amdgcn_mfma_f32_16x16x32_bf16(a[kt], bf[kt][nt], acc[nt], 0, 0, 0);
        }
#pragma unroll
        for (int r = 0; r < 4; ++r) {
            int orow = t * 16 + kgrp * 4 + r;
            if (orow < n) {
                int s0 = rowptr[orow], s1 = rowptr[orow + 1];
                for (int s = s0; s < s1; ++s) {
                    uint2 q = *(const uint2*)(part + (size_t)s * 64 + mrow * 4);
                    acc[0][r] += bflo(q.x);
                    acc[1][r] += bfhi(q.x);
                    acc[2][r] += bflo(q.y);
                    acc[3][r] += bfhi(q.y);
                }
                if constexpr (sizeof(TOUT) == 4) {
#pragma unroll
                    for (int nt = 0; nt < 4; ++nt)
                        ((float*)xout)[(size_t)orow * 64 + nt * 16 + mrow] = acc[nt][r];
                } else {
#pragma unroll
                    for (int nt = 0; nt < 4; ++nt)
                        ((unsigned short*)xout)[(size_t)orow * 64 + nt * 16 + mrow] =
                            (unsigned short)f2bf(acc[nt][r]);
                }
            }
        }
    };

    for (int tt = wid; tt < ntiles2; tt += nwaves) {
        body(tt * 2);
        body(tt * 2 + 1);
    }
}

// ---------- off-center taps (MFMA): part[dst] = x[pairJ] @ W[k]  (no atomics) ---------
template <int C, typename TIN>
__global__ __launch_bounds__(256) void offc_mfma_kernel(
        const TIN* __restrict__ xin, const float* __restrict__ Wsrc,
        const int* __restrict__ cnt, const int2* __restrict__ pairIJ,
        const int* __restrict__ rowptr,
        unsigned short* __restrict__ part, int n) {
    constexpr int KT = C / 32;
    __shared__ int pfx[KK + 1];
    int lane = threadIdx.x & 63;
    int wid = threadIdx.x >> 6;
    int mrow = lane & 15;
    int kgrp = lane >> 4;
    if (threadIdx.x == 0) {
        int acc = 0; pfx[0] = 0;
        for (int k = 0; k < KK; ++k) {
            int ck = min(cnt[k * CNT_STRIDE], CAP);
            acc += (ck + 127) >> 7;
            pfx[k + 1] = acc;
        }
    }
    __syncthreads();
    int T = pfx[KK];
    for (int g = blockIdx.x; g < T; g += gridDim.x) {
        int k = 0;
        while (pfx[k + 1] <= g) ++k;
        int chunk = g - pfx[k];
        const float* Wk = Wsrc + (size_t)k * C * 64;
        bf16x8 bf[KT][4];
#pragma unroll
        for (int kt = 0; kt < KT; ++kt)
#pragma unroll
            for (int nt = 0; nt < 4; ++nt)
#pragma unroll
                for (int j = 0; j < 8; ++j)
                    bf[kt][nt][j] = f2bf(Wk[(kt * 32 + kgrp * 8 + j) * 64 + nt * 16 + mrow]);
        int base = k * CAP + chunk * 128 + wid * 32;
#pragma unroll
        for (int half = 0; half < 2; ++half) {
            int b16 = base + half * 16;
            int2 pA = pairIJ[b16 + mrow];                  // {(i<<5)|lt, j}; sentinel i=n
            int jrow = pA.y;
            bf16x8 a[KT];
            if constexpr (sizeof(TIN) == 4) {
                const float* xr = (const float*)xin + (size_t)jrow * C + kgrp * 8;
#pragma unroll
                for (int kt = 0; kt < KT; ++kt) {
                    float4 x0 = *(const float4*)(xr + kt * 32);
                    float4 x1 = *(const float4*)(xr + kt * 32 + 4);
                    a[kt][0] = f2bf(x0.x); a[kt][1] = f2bf(x0.y);
                    a[kt][2] = f2bf(x0.z); a[kt][3] = f2bf(x0.w);
                    a[kt][4] = f2bf(x1.x); a[kt][5] = f2bf(x1.y);
                    a[kt][6] = f2bf(x1.z); a[kt][7] = f2bf(x1.w);
                }
            } else {
                const unsigned short* xr = (const unsigned short*)xin + (size_t)jrow * C + kgrp * 8;
#pragma unroll
                for (int kt = 0; kt < KT; ++kt)
                    a[kt] = *(const bf16x8*)(xr + kt * 32);
            }
            f32x4 zero = {0.f, 0.f, 0.f, 0.f};
            f32x4 acc[4];
#pragma unroll
            for (int nt = 0; nt < 4; ++nt) {
                acc[nt] = zero;
#pragma unroll
                for (int kt = 0; kt < KT; ++kt)
                    acc[nt] = __builtin_amdgcn_mfma_f32_16x16x32_bf16(a[kt], bf[kt][nt], acc[nt], 0, 0, 0);
            }
#pragma unroll
            for (int r = 0; r < 4; ++r) {
                int pk = __shfl(pA.x, kgrp * 4 + r);       // pair (kgrp*4+r)'s packed i
                int ir = pk >> 5;
                if (ir < n) {
                    int dst = rowptr[ir] + (pk & 31);
                    if (dst < PCAP) {
                        uint2 q;
                        q.x = (unsigned)(unsigned short)f2bf(acc[0][r]) |
                              ((unsigned)(unsigned short)f2bf(acc[1][r]) << 16);
                        q.y = (unsigned)(unsigned short)f2bf(acc[2][r]) |
                              ((unsigned)(unsigned short)f2bf(acc[3][r]) << 16);
                        *(uint2*)(part + (size_t)dst * 64 + mrow * 4) = q;
                    }
                }
            }
        }
    }
}

extern "C" void kernel_launch(void* const* d_in, const int* in_sizes, int n_in,
                              void* d_out, int out_size, void* d_ws, size_t ws_size,
                              hipStream_t stream) {
    const float* feats = (const float*)d_in[0];   // [N,32] fp32
    const int*   coors = (const int*)d_in[1];     // [N,4] int32
    const float* W1 = (const float*)d_in[3];      // [27,32,64] fp32
    const float* W2 = (const float*)d_in[4];      // [27,64,64] fp32
    float* out = (float*)d_out;                   // [N,64] fp32

    int n = in_sizes[0] / CIN;                    // 200000

    // ws: x1(bf16) | bitmap | prefix | flats | percnt | rowptr | bsum256 | done | cnt | pairIJ | part
    char* ws = (char*)d_ws;
    size_t off = 0;
    unsigned short* x1 = (unsigned short*)(ws + off);     // [N][64] bf16
    off += ((size_t)n * COUT * 2 + 255) & ~(size_t)255;
    unsigned long long* bitmap = (unsigned long long*)(ws + off);
    off += ((size_t)NWORDS * 8 + 255) & ~(size_t)255;
    int* prefix = (int*)(ws + off);
    off += ((size_t)NWORDS * 4 + 255) & ~(size_t)255;
    int* flats = (int*)(ws + off);
    off += ((size_t)n * 4 + 255) & ~(size_t)255;
    int* percnt = (int*)(ws + off);
    off += ((size_t)n * 4 + 255) & ~(size_t)255;
    int* rowptr = (int*)(ws + off);
    off += ((size_t)(n + 1) * 4 + 255) & ~(size_t)255;
    int* bsum256 = (int*)(ws + off);
    off += (1024 * 4 + 255) & ~(size_t)255;
    int* done = (int*)(ws + off);
    off += 256;
    int* cnt = (int*)(ws + off);
    off += ((size_t)KK * CNT_STRIDE * 4 + 255) & ~(size_t)255;
    int2* pairIJ = (int2*)(ws + off);
    off += ((size_t)KK * CAP * 8 + 4096 + 255) & ~(size_t)255;
    unsigned short* part = (unsigned short*)(ws + off);   // PCAP * 64 * 2 = 32 MB

    int nbuild = (n + 255) / 256;                 // 782
    int nscan = (n + SCAN_B - 1) / SCAN_B;        // 196
    int ntiles = (n + 15) / 16;                   // 12500
    int ntiles2 = (ntiles + 1) / 2;
    int cgrid = (ntiles2 + 3) / 4;                // 2 m-tiles per wave

    init_kernel<<<(NWORDS + 255) / 256, 256, 0, stream>>>(bitmap, cnt, done);
    fill_kernel<<<(n + 255) / 256, 256, 0, stream>>>(coors, flats, bitmap, n);
    prefix_kernel<<<(NWORDS + 255) / 256, 256, 0, stream>>>(flats, prefix, n);
    build_pairs_kernel<<<nbuild, 256, 0, stream>>>(
        flats, bitmap, prefix, cnt, pairIJ, percnt, bsum256, done, n);
    scan3_kernel<<<nscan, 256, 0, stream>>>(percnt, bsum256, rowptr, n);
    // layer 1: feats [N,32] fp32 -> x1 [N,64] bf16   (offc first, center consumes partials)
    offc_mfma_kernel<CIN, float><<<OFFC_GRID, 256, 0, stream>>>(
        feats, W1, cnt, pairIJ, rowptr, part, n);
    center_mfma_kernel<CIN, float, unsigned short><<<cgrid, 256, 0, stream>>>(
        feats, W1 + (size_t)13 * CIN * COUT, rowptr, part, x1, n);
    // layer 2: x1 [N,64] bf16 -> out [N,64] fp32
    offc_mfma_kernel<COUT, unsigned short><<<OFFC_GRID, 256, 0, stream>>>(
        x1, W2, cnt, pairIJ, rowptr, part, n);
    center_mfma_kernel<COUT, unsigned short, float><<<cgrid, 256, 0, stream>>>(
        x1, W2 + (size_t)13 * COUT * COUT, rowptr, part, out, n);
}

// Round 13
// 149.628 us; speedup vs baseline: 1.0234x; 1.0234x over previous
//
#include <hip/hip_runtime.h>
#include <hip/hip_bf16.h>

// Problem constants (match reference: shape=[15,400,400], batch_size=2)
#define DD 15
#define HH 400
#define WW 400
#define CIN 32
#define COUT 64
#define KK 27
#define NVOX (2 * DD * HH * WW)        // 4,800,000
#define NWORDS (NVOX / 64)              // 75,000 bitmap words
#define CAP 32768                       // per-k pair capacity (actual ~8.3k), mult of 128
#define CNT_STRIDE 64                   // one counter per 256B line
#define OFFC_GRID 1024                  // coarsened: ~2 contiguous chunks per block
#define PCAP 262144                     // total pair slots (actual ~217k)
#define SCAN_B 1024                     // elements per scan block

typedef short bf16x8 __attribute__((ext_vector_type(8)));
typedef float f32x4  __attribute__((ext_vector_type(4)));

__device__ inline short f2bf(float f) {               // f32 -> bf16 RNE
    unsigned u = __float_as_uint(f);
    return (short)((u + 0x7FFFu + ((u >> 16) & 1u)) >> 16);
}
__device__ inline float bflo(unsigned u) { return __uint_as_float(u << 16); }
__device__ inline float bfhi(unsigned u) { return __uint_as_float(u & 0xFFFF0000u); }

// ---------- init: bitmap = 0, cnt = 0 -------------------------------------------------
__global__ void init_kernel(unsigned long long* __restrict__ bitmap,
                            int* __restrict__ cnt) {
    int t = blockIdx.x * blockDim.x + threadIdx.x;
    if (t < KK * CNT_STRIDE) cnt[t] = 0;
    int stride = gridDim.x * blockDim.x;
    for (int w = t; w < NWORDS; w += stride) bitmap[w] = 0ull;
}

// ---------- fill: flats[i] = flat(coors[i]); set presence bit -------------------------
__global__ void fill_kernel(const int* __restrict__ coors,
                            int* __restrict__ flats,
                            unsigned long long* __restrict__ bitmap, int n) {
    int i = blockIdx.x * blockDim.x + threadIdx.x;
    if (i >= n) return;
    int b = coors[i * 4 + 0];
    int z = coors[i * 4 + 1];
    int y = coors[i * 4 + 2];
    int x = coors[i * 4 + 3];
    int f = ((b * DD + z) * HH + y) * WW + x;
    flats[i] = f;
    atomicOr(&bitmap[f >> 6], 1ull << (f & 63));
}

// ---------- prefix[w] = lower_bound(flats, w*64)  (rank base per bitmap word) ---------
__global__ void prefix_kernel(const int* __restrict__ flats,
                              int* __restrict__ prefix, int n) {
    int w = blockIdx.x * blockDim.x + threadIdx.x;
    if (w >= NWORDS) return;
    int target = w << 6;
    int lo = 0, hi = n;
    while (lo < hi) {
        int mid = (lo + hi) >> 1;
        if (flats[mid] < target) lo = mid + 1; else hi = mid;
    }
    prefix[w] = lo;
}

__device__ inline bool bm_test(const unsigned long long* __restrict__ bitmap, int f) {
    return (bitmap[f >> 6] >> (f & 63)) & 1ull;
}
__device__ inline int bm_rank(const unsigned long long* __restrict__ bitmap,
                              const int* __restrict__ prefix, int f) {
    int w = f >> 6, b = f & 63;       // bit known set
    unsigned long long m = bitmap[w];
    return prefix[w] + __popcll(m & ((1ull << b) - 1ull));
}

// ---------- off-center pair lists: one voxel/thread; emits packed (i*32+lt, j) --------
__global__ __launch_bounds__(256) void build_pairs_kernel(
        const int* __restrict__ flats,
        const unsigned long long* __restrict__ bitmap,
        const int* __restrict__ prefix,
        int* __restrict__ cnt, int* __restrict__ pairI,
        int* __restrict__ pairJ, int* __restrict__ percnt, int n) {
    __shared__ int lcnt[KK];
    __shared__ int lbase[KK];
    __shared__ int lpos[KK];
    int i = blockIdx.x * blockDim.x + threadIdx.x;
    if (threadIdx.x < KK) { lcnt[threadIdx.x] = 0; lpos[threadIdx.x] = 0; }
    __syncthreads();

    int f0 = 0, x = 0;
    unsigned vmask = 0;                // 27-bit tap-validity mask
    bool act = (i < n);
    if (act) {
        f0 = flats[i];
        x = f0 % WW;
        int rem = f0 / WW;             // (b*DD+z)*HH + y
        int y = rem % HH;
        int z = (rem / HH) % DD;
#pragma unroll
        for (int p = 0; p < 9; ++p) {
            int dz = p / 3 - 1, dy = p % 3 - 1;
            int zn = z + dz, yn = y + dy;
            if (zn < 0 || zn >= DD || yn < 0 || yn >= HH) continue;
            int fn = f0 + dz * (HH * WW) + dy * WW;
            int kb = p * 3;
            if (x > 0 && bm_test(bitmap, fn - 1)) {
                vmask |= 1u << kb; atomicAdd(&lcnt[kb], 1);
            }
            if (kb + 1 != 13 && bm_test(bitmap, fn)) {
                vmask |= 1u << (kb + 1); atomicAdd(&lcnt[kb + 1], 1);
            }
            if (x < WW - 1 && bm_test(bitmap, fn + 1)) {
                vmask |= 1u << (kb + 2); atomicAdd(&lcnt[kb + 2], 1);
            }
        }
        percnt[i] = __popc(vmask);
    }
    __syncthreads();
    if (threadIdx.x < KK && lcnt[threadIdx.x] > 0)
        lbase[threadIdx.x] = atomicAdd(&cnt[threadIdx.x * CNT_STRIDE], lcnt[threadIdx.x]);
    __syncthreads();
    if (act && vmask) {
        int lt = 0;                    // thread-local slot within voxel i's CSR segment
#pragma unroll
        for (int p = 0; p < 9; ++p) {
            int kb = p * 3;
            if (!(vmask & (7u << kb))) continue;
            int dz = p / 3 - 1, dy = p % 3 - 1;
            int fn = f0 + dz * (HH * WW) + dy * WW;
#pragma unroll
            for (int d = 0; d < 3; ++d) {
                int k = kb + d;
                if (!(vmask & (1u << k))) continue;
                int j = bm_rank(bitmap, prefix, fn + d - 1);
                int pos = lbase[k] + atomicAdd(&lpos[k], 1);
                if (pos < CAP) {
                    pairI[k * CAP + pos] = (i << 5) | lt;
                    pairJ[k * CAP + pos] = j;
                }
                ++lt;
            }
        }
    }
}

// ---------- scan1 (blocks < nscan) + pad_pairs (blocks >= nscan) ----------------------
__global__ void scan1pad_kernel(const int* __restrict__ pc, int* __restrict__ bsum,
                                const int* __restrict__ cnt, int* __restrict__ pairI,
                                int* __restrict__ pairJ, int n, int nscan) {
    __shared__ int red[256];
    if ((int)blockIdx.x >= nscan) {                    // pad role
        int k = blockIdx.x - nscan;
        int ck = min(cnt[k * CNT_STRIDE], CAP);
        int ckp = min((ck + 127) & ~127, CAP);
        for (int pos = ck + (int)threadIdx.x; pos < ckp; pos += blockDim.x) {
            pairI[k * CAP + pos] = (n << 5);           // sentinel: i = n -> store skipped
            pairJ[k * CAP + pos] = 0;                  // valid row, read harmless
        }
        return;
    }
    int base = blockIdx.x * SCAN_B;
    int s = 0;
#pragma unroll
    for (int u = 0; u < 4; ++u) {
        int idx = base + u * 256 + threadIdx.x;
        if (idx < n) s += pc[idx];
    }
    red[threadIdx.x] = s; __syncthreads();
    for (int o = 128; o > 0; o >>= 1) {
        if ((int)threadIdx.x < o) red[threadIdx.x] += red[threadIdx.x + o];
        __syncthreads();
    }
    if (threadIdx.x == 0) bsum[blockIdx.x] = red[0];
}

// ---------- scan3: rowptr = exclusive prefix (block base computed in-block) -----------
__global__ void scan3_kernel(const int* __restrict__ pc, const int* __restrict__ bsum,
                             int* __restrict__ rowptr, int n, int nscan) {
    __shared__ int ts[256];
    __shared__ int bs[256];
    // block base = sum of bsum[0 .. blockIdx.x-1]
    int v = ((int)threadIdx.x < nscan && (int)threadIdx.x < (int)blockIdx.x)
                ? bsum[threadIdx.x] : 0;
    bs[threadIdx.x] = v; __syncthreads();
    for (int o = 128; o > 0; o >>= 1) {
        if ((int)threadIdx.x < o) bs[threadIdx.x] += bs[threadIdx.x + o];
        __syncthreads();
    }
    int bbase = bs[0];

    int base = blockIdx.x * SCAN_B + threadIdx.x * 4;
    int e[4]; int s = 0;
#pragma unroll
    for (int u = 0; u < 4; ++u) {
        int idx = base + u;
        e[u] = (idx < n) ? pc[idx] : 0;
        s += e[u];
    }
    ts[threadIdx.x] = s; __syncthreads();
    for (int o = 1; o < 256; o <<= 1) {        // inclusive H-S scan
        int t = ((int)threadIdx.x >= o) ? ts[threadIdx.x - o] : 0;
        __syncthreads();
        ts[threadIdx.x] += t;
        __syncthreads();
    }
    int run = ts[threadIdx.x] - s + bbase;     // exclusive thread base
#pragma unroll
    for (int u = 0; u < 4; ++u) {
        int idx = base + u;
        if (idx < n) rowptr[idx] = run;
        run += e[u];
        if (idx == n - 1) rowptr[n] = run;
    }
}

// ---------- center tap (MFMA) + CSR partial reduce: out written exactly once ----------
// TIN: float (layer 1) or unsigned short/bf16 (layer 2). TOUT likewise.
// part is bf16 fragment-native: part[dst][mrow*4 + nt], 128 B per row.
template <int C, typename TIN, typename TOUT>
__global__ __launch_bounds__(256) void center_mfma_kernel(
        const TIN* __restrict__ xin, const float* __restrict__ Wc,  // Wc = W + 13*C*64
        const int* __restrict__ rowptr, const unsigned short* __restrict__ part,
        TOUT* __restrict__ xout, int n) {
    constexpr int KT = C / 32;
    int lane = threadIdx.x & 63;
    int mrow = lane & 15;            // A row / B col / D col
    int kgrp = lane >> 4;            // k-group (8 k's per group)
    int wid = (blockIdx.x * blockDim.x + threadIdx.x) >> 6;
    int nwaves = (gridDim.x * blockDim.x) >> 6;

    bf16x8 bf[KT][4];                // B fragments: [k-tile][n-tile]
#pragma unroll
    for (int kt = 0; kt < KT; ++kt)
#pragma unroll
        for (int nt = 0; nt < 4; ++nt)
#pragma unroll
            for (int j = 0; j < 8; ++j)
                bf[kt][nt][j] = f2bf(Wc[(kt * 32 + kgrp * 8 + j) * 64 + nt * 16 + mrow]);

    int ntiles = (n + 15) >> 4;
    for (int t = wid; t < ntiles; t += nwaves) {
        int row = t * 16 + mrow;
        f32x4 zero = {0.f, 0.f, 0.f, 0.f};
        bf16x8 a[KT];
        if (row < n) {
            if constexpr (sizeof(TIN) == 4) {
                const float* xr = (const float*)xin + (size_t)row * C + kgrp * 8;
#pragma unroll
                for (int kt = 0; kt < KT; ++kt) {
                    float4 x0 = *(const float4*)(xr + kt * 32);
                    float4 x1 = *(const float4*)(xr + kt * 32 + 4);
                    a[kt][0] = f2bf(x0.x); a[kt][1] = f2bf(x0.y);
                    a[kt][2] = f2bf(x0.z); a[kt][3] = f2bf(x0.w);
                    a[kt][4] = f2bf(x1.x); a[kt][5] = f2bf(x1.y);
                    a[kt][6] = f2bf(x1.z); a[kt][7] = f2bf(x1.w);
                }
            } else {
                const unsigned short* xr = (const unsigned short*)xin + (size_t)row * C + kgrp * 8;
#pragma unroll
                for (int kt = 0; kt < KT; ++kt)
                    a[kt] = *(const bf16x8*)(xr + kt * 32);
            }
        } else {
#pragma unroll
            for (int kt = 0; kt < KT; ++kt)
#pragma unroll
                for (int j = 0; j < 8; ++j) a[kt][j] = 0;
        }
        f32x4 acc[4];
#pragma unroll
        for (int nt = 0; nt < 4; ++nt) {
            acc[nt] = zero;
#pragma unroll
            for (int kt = 0; kt < KT; ++kt)
                acc[nt] = __builtin_amdgcn_mfma_f32_16x16x32_bf16(a[kt], bf[kt][nt], acc[nt], 0, 0, 0);
        }
        // add off-center partial rows (CSR segment per output row), then store once
#pragma unroll
        for (int r = 0; r < 4; ++r) {
            int orow = t * 16 + kgrp * 4 + r;
            if (orow < n) {
                int s0 = rowptr[orow], s1 = rowptr[orow + 1];
                for (int s = s0; s < s1; ++s) {
                    uint2 q = *(const uint2*)(part + (size_t)s * 64 + mrow * 4);
                    acc[0][r] += bflo(q.x);
                    acc[1][r] += bfhi(q.x);
                    acc[2][r] += bflo(q.y);
                    acc[3][r] += bfhi(q.y);
                }
                if constexpr (sizeof(TOUT) == 4) {
#pragma unroll
                    for (int nt = 0; nt < 4; ++nt)
                        ((float*)xout)[(size_t)orow * 64 + nt * 16 + mrow] = acc[nt][r];
                } else {
#pragma unroll
                    for (int nt = 0; nt < 4; ++nt)
                        ((unsigned short*)xout)[(size_t)orow * 64 + nt * 16 + mrow] =
                            (unsigned short)f2bf(acc[nt][r]);
                }
            }
        }
    }
}

// ---------- off-center taps (MFMA): part[dst] = x[pairJ] @ W[k]  (no atomics) ---------
// Coarsened: each block owns a CONTIGUOUS span of chunks; weight panel reloaded only
// when k changes within the span (consecutive chunks nearly always share k).
template <int C, typename TIN>
__global__ __launch_bounds__(256) void offc_mfma_kernel(
        const TIN* __restrict__ xin, const float* __restrict__ Wsrc,
        const int* __restrict__ cnt, const int* __restrict__ pairI,
        const int* __restrict__ pairJ, const int* __restrict__ rowptr,
        unsigned short* __restrict__ part, int n) {
    constexpr int KT = C / 32;
    __shared__ int pfx[KK + 1];
    int lane = threadIdx.x & 63;
    int wid = threadIdx.x >> 6;
    int mrow = lane & 15;
    int kgrp = lane >> 4;
    if (threadIdx.x == 0) {
        int acc = 0; pfx[0] = 0;
        for (int k = 0; k < KK; ++k) {
            int ck = min(cnt[k * CNT_STRIDE], CAP);
            acc += (ck + 127) >> 7;
            pfx[k + 1] = acc;
        }
    }
    __syncthreads();
    int T = pfx[KK];
    int span = (T + gridDim.x - 1) / gridDim.x;
    int g0 = blockIdx.x * span;
    int g1 = min(g0 + span, T);
    int kcur = -1;
    bf16x8 bf[KT][4];
    for (int g = g0; g < g1; ++g) {
        int k = (kcur < 0) ? 0 : kcur;
        while (pfx[k + 1] <= g) ++k;
        if (k != kcur) {               // load weight panel only on k change
            const float* Wk = Wsrc + (size_t)k * C * 64;
#pragma unroll
            for (int kt = 0; kt < KT; ++kt)
#pragma unroll
                for (int nt = 0; nt < 4; ++nt)
#pragma unroll
                    for (int j = 0; j < 8; ++j)
                        bf[kt][nt][j] = f2bf(Wk[(kt * 32 + kgrp * 8 + j) * 64 + nt * 16 + mrow]);
            kcur = k;
        }
        int chunk = g - pfx[k];
        int base = k * CAP + chunk * 128 + wid * 32;
#pragma unroll
        for (int half = 0; half < 2; ++half) {
            int b16 = base + half * 16;
            int jrow = pairJ[b16 + mrow];                  // sentinel -> row 0, harmless
            bf16x8 a[KT];
            if constexpr (sizeof(TIN) == 4) {
                const float* xr = (const float*)xin + (size_t)jrow * C + kgrp * 8;
#pragma unroll
                for (int kt = 0; kt < KT; ++kt) {
                    float4 x0 = *(const float4*)(xr + kt * 32);
                    float4 x1 = *(const float4*)(xr + kt * 32 + 4);
                    a[kt][0] = f2bf(x0.x); a[kt][1] = f2bf(x0.y);
                    a[kt][2] = f2bf(x0.z); a[kt][3] = f2bf(x0.w);
                    a[kt][4] = f2bf(x1.x); a[kt][5] = f2bf(x1.y);
                    a[kt][6] = f2bf(x1.z); a[kt][7] = f2bf(x1.w);
                }
            } else {
                const unsigned short* xr = (const unsigned short*)xin + (size_t)jrow * C + kgrp * 8;
#pragma unroll
                for (int kt = 0; kt < KT; ++kt)
                    a[kt] = *(const bf16x8*)(xr + kt * 32);
            }
            f32x4 zero = {0.f, 0.f, 0.f, 0.f};
            f32x4 acc[4];
#pragma unroll
            for (int nt = 0; nt < 4; ++nt) {
                acc[nt] = zero;
#pragma unroll
                for (int kt = 0; kt < KT; ++kt)
                    acc[nt] = __builtin_amdgcn_mfma_f32_16x16x32_bf16(a[kt], bf[kt][nt], acc[nt], 0, 0, 0);
            }
#pragma unroll
            for (int r = 0; r < 4; ++r) {
                int pk = pairI[b16 + kgrp * 4 + r];
                int ir = pk >> 5;
                if (ir < n) {
                    int dst = rowptr[ir] + (pk & 31);
                    if (dst < PCAP) {
                        // pack 4 partials (nt=0..3) as bf16 -> one 8B store
                        uint2 q;
                        q.x = (unsigned)(unsigned short)f2bf(acc[0][r]) |
                              ((unsigned)(unsigned short)f2bf(acc[1][r]) << 16);
                        q.y = (unsigned)(unsigned short)f2bf(acc[2][r]) |
                              ((unsigned)(unsigned short)f2bf(acc[3][r]) << 16);
                        *(uint2*)(part + (size_t)dst * 64 + mrow * 4) = q;
                    }
                }
            }
        }
    }
}

extern "C" void kernel_launch(void* const* d_in, const int* in_sizes, int n_in,
                              void* d_out, int out_size, void* d_ws, size_t ws_size,
                              hipStream_t stream) {
    const float* feats = (const float*)d_in[0];   // [N,32] fp32
    const int*   coors = (const int*)d_in[1];     // [N,4] int32
    const float* W1 = (const float*)d_in[3];      // [27,32,64] fp32
    const float* W2 = (const float*)d_in[4];      // [27,64,64] fp32
    float* out = (float*)d_out;                   // [N,64] fp32

    int n = in_sizes[0] / CIN;                    // 200000

    // ws layout: x1(bf16) | bitmap | prefix | flats | percnt | rowptr | bsum | cnt | pairI | pairJ | part(bf16)
    char* ws = (char*)d_ws;
    size_t off = 0;
    unsigned short* x1 = (unsigned short*)(ws + off);     // [N][64] bf16
    off += ((size_t)n * COUT * 2 + 255) & ~(size_t)255;
    unsigned long long* bitmap = (unsigned long long*)(ws + off);
    off += ((size_t)NWORDS * 8 + 255) & ~(size_t)255;
    int* prefix = (int*)(ws + off);
    off += ((size_t)NWORDS * 4 + 255) & ~(size_t)255;
    int* flats = (int*)(ws + off);
    off += ((size_t)n * 4 + 255) & ~(size_t)255;
    int* percnt = (int*)(ws + off);
    off += ((size_t)n * 4 + 255) & ~(size_t)255;
    int* rowptr = (int*)(ws + off);
    off += ((size_t)(n + 1) * 4 + 255) & ~(size_t)255;
    int* bsum = (int*)(ws + off);
    off += (256 * 4 + 255) & ~(size_t)255;
    int* cnt = (int*)(ws + off);
    off += ((size_t)KK * CNT_STRIDE * 4 + 255) & ~(size_t)255;
    int* pairI = (int*)(ws + off);
    off += ((size_t)KK * CAP * 4 + 4096 + 255) & ~(size_t)255;
    int* pairJ = (int*)(ws + off);
    off += ((size_t)KK * CAP * 4 + 4096 + 255) & ~(size_t)255;
    unsigned short* part = (unsigned short*)(ws + off);   // PCAP * 64 * 2 = 32 MB

    int nscan = (n + SCAN_B - 1) / SCAN_B;        // 196 blocks (<= 256)
    int ntiles = (n + 15) / 16;                   // 12500
    int cgrid = (ntiles + 3) / 4;                 // 1 m-tile per wave

    init_kernel<<<(NWORDS + 255) / 256, 256, 0, stream>>>(bitmap, cnt);
    fill_kernel<<<(n + 255) / 256, 256, 0, stream>>>(coors, flats, bitmap, n);
    prefix_kernel<<<(NWORDS + 255) / 256, 256, 0, stream>>>(flats, prefix, n);
    build_pairs_kernel<<<(n + 255) / 256, 256, 0, stream>>>(
        flats, bitmap, prefix, cnt, pairI, pairJ, percnt, n);
    scan1pad_kernel<<<nscan + KK, 256, 0, stream>>>(percnt, bsum, cnt, pairI, pairJ, n, nscan);
    scan3_kernel<<<nscan, 256, 0, stream>>>(percnt, bsum, rowptr, n, nscan);
    // layer 1: feats [N,32] fp32 -> x1 [N,64] bf16   (offc first, center consumes partials)
    offc_mfma_kernel<CIN, float><<<OFFC_GRID, 256, 0, stream>>>(
        feats, W1, cnt, pairI, pairJ, rowptr, part, n);
    center_mfma_kernel<CIN, float, unsigned short><<<cgrid, 256, 0, stream>>>(
        feats, W1 + (size_t)13 * CIN * COUT, rowptr, part, x1, n);
    // layer 2: x1 [N,64] bf16 -> out [N,64] fp32
    offc_mfma_kernel<COUT, unsigned short><<<OFFC_GRID, 256, 0, stream>>>(
        x1, W2, cnt, pairI, pairJ, rowptr, part, n);
    center_mfma_kernel<COUT, unsigned short, float><<<cgrid, 256, 0, stream>>>(
        x1, W2 + (size_t)13 * COUT * COUT, rowptr, part, out, n);
}